// Round 1
// baseline (295.571 us; speedup 1.0000x reference)
//
#include <hip/hip_runtime.h>
#include <hip/hip_bf16.h>
#include <stdint.h>

// Problem constants
#define B_    32
#define SW_   512
#define SL_   256
#define H_    768
#define NL_   4
#define NOUT_ 400
#define M_    (B_*SL_)   // 8192 pooled rows
#define NPAD_ 512        // N padded to 4 x 128-wide tiles

// Tiled (MFMA fragment-linear) layout for a [R][768] bf16 matrix:
//   elem (r, k) -> ((r>>4)*(H_/8) + (k>>3))*128 + (r&15)*8 + (k&7)
// A 16x32 MFMA fragment for rows [rt*16,+16), k [k0,+32) is then the 1024B
// chunk at ((rt*96 + k0/8)*128)*2 bytes, lane L reading 16B at +L*16.

typedef __attribute__((ext_vector_type(4))) float  f32x4;
typedef __attribute__((ext_vector_type(8))) short  bf16x8;
typedef __attribute__((ext_vector_type(4))) short  bf16x4;

__device__ __forceinline__ unsigned short f2bf(float f) {
  union { float f; unsigned int u; } x; x.f = f;
  unsigned int u = x.u;
  return (unsigned short)((u + 0x7fffu + ((u >> 16) & 1u)) >> 16);
}

// ---------------------------------------------------------------------------
// Kernel 1: blocks [0,32): inclusive-scan bert_lens per example -> starts.
//           blocks [32,224): cast proj_w to bf16 tiled layout (pad to 512).
// ---------------------------------------------------------------------------
__global__ __launch_bounds__(256) void prep_kernel(const int* __restrict__ lens,
                                                   const float* __restrict__ projw,
                                                   int* __restrict__ starts,
                                                   unsigned short* __restrict__ wp) {
  const int blk = blockIdx.x;
  const int t = threadIdx.x;
  if (blk < B_) {
    __shared__ int s[SL_];
    int v = lens[blk*SL_ + t];
    s[t] = v;
    __syncthreads();
    for (int off = 1; off < SL_; off <<= 1) {
      int add = (t >= off) ? s[t - off] : 0;
      __syncthreads();
      s[t] += add;
      __syncthreads();
    }
    starts[blk*SL_ + t] = s[t] - v;  // exclusive prefix
  } else {
    // 192 blocks x 256 threads x 8 elems = 393216 = NPAD_*H_
    const int base = (blk - B_) * 2048;
#pragma unroll
    for (int i = 0; i < 8; ++i) {
      int idx = base + i*256 + t;
      int n = idx / H_;
      int k = idx - n*H_;
      float v = (n < NOUT_) ? projw[n*H_ + k] : 0.0f;
      int off = ((n >> 4)*(H_/8) + (k >> 3))*128 + (n & 15)*8 + (k & 7);
      wp[off] = f2bf(v);
    }
  }
}

// ---------------------------------------------------------------------------
// Kernel 2: one block per pooled row (b,word j). Fused softmax mix + gamma +
// ragged mean. 192 threads, thread t covers k = 4t..4t+3 via float4 loads.
// Writes bf16 in tiled layout.
// ---------------------------------------------------------------------------
__global__ __launch_bounds__(192) void pool_kernel(const int* __restrict__ lens,
                                                   const int* __restrict__ starts,
                                                   const float* __restrict__ hidden,
                                                   const float* __restrict__ mixw,
                                                   const float* __restrict__ gamma,
                                                   unsigned short* __restrict__ pooled) {
  const int m = blockIdx.x;          // 0..8191
  const int b = m >> 8;              // /SL_
  const int t = threadIdx.x;         // 0..191
  const int len = lens[m];
  const int start = starts[m];

  // softmax over 4 mix weights
  float w0 = mixw[0], w1 = mixw[1], w2 = mixw[2], w3 = mixw[3];
  float mx = fmaxf(fmaxf(w0, w1), fmaxf(w2, w3));
  float ew[NL_];
  ew[0] = __expf(w0 - mx); ew[1] = __expf(w1 - mx);
  ew[2] = __expf(w2 - mx); ew[3] = __expf(w3 - mx);
  float esum = ew[0] + ew[1] + ew[2] + ew[3];
  int cnt = (len > 0) ? len : 1;
  float scale = gamma[0] / (esum * (float)cnt);

  f32x4 acc = {0.0f, 0.0f, 0.0f, 0.0f};
  for (int p = 0; p < len; ++p) {
#pragma unroll
    for (int l = 0; l < NL_; ++l) {
      const f32x4* src = reinterpret_cast<const f32x4*>(
          hidden + ((size_t)(l*B_ + b)*SW_ + (size_t)(start + p)) * H_);
      f32x4 v = src[t];
      acc += v * ew[l];
    }
  }

  const int k = t * 4;
  const int off = ((m >> 4)*(H_/8) + (k >> 3))*128 + (m & 15)*8 + (k & 7);
  bf16x4 o;
  o[0] = (short)f2bf(acc[0] * scale);
  o[1] = (short)f2bf(acc[1] * scale);
  o[2] = (short)f2bf(acc[2] * scale);
  o[3] = (short)f2bf(acc[3] * scale);
  *reinterpret_cast<bf16x4*>(pooled + off) = o;
}

// ---------------------------------------------------------------------------
// Kernel 3: GEMM out[m][n] = sum_k pooled[m][k] * W[n][k], bf16 MFMA 16x16x32.
// Block tile 128x128, 4 waves (2x2) each 64x64 (4x4 16x16 accs).
// Fragments loaded directly from global (fragment-linear layout, L2-resident),
// no LDS, K software-pipelined.
// ---------------------------------------------------------------------------
__global__ __launch_bounds__(256) void gemm_kernel(const unsigned short* __restrict__ pooled,
                                                   const unsigned short* __restrict__ wp,
                                                   float* __restrict__ out) {
  const int lane = threadIdx.x & 63;
  const int wave = threadIdx.x >> 6;
  const int wm = wave >> 1, wn = wave & 1;
  const int mbase = blockIdx.x * 128 + wm * 64;
  const int nbase = blockIdx.y * 128 + wn * 64;
  const int mt0 = mbase >> 4;
  const int nt0 = nbase >> 4;

  f32x4 acc[4][4];
#pragma unroll
  for (int i = 0; i < 4; ++i)
#pragma unroll
    for (int j = 0; j < 4; ++j)
      acc[i][j] = (f32x4){0.0f, 0.0f, 0.0f, 0.0f};

#define LOADA(k0, mt) \
  (*reinterpret_cast<const bf16x8*>(pooled + ((size_t)((mt0 + (mt))*(H_/8) + ((k0) >> 3)))*128 + lane*8))
#define LOADB(k0, nt) \
  (*reinterpret_cast<const bf16x8*>(wp + ((size_t)((nt0 + (nt))*(H_/8) + ((k0) >> 3)))*128 + lane*8))

  bf16x8 a[4], b[4];
#pragma unroll
  for (int i = 0; i < 4; ++i) { a[i] = LOADA(0, i); b[i] = LOADB(0, i); }

  for (int k0 = 32; k0 < H_; k0 += 32) {
    bf16x8 a2[4], b2[4];
#pragma unroll
    for (int i = 0; i < 4; ++i) { a2[i] = LOADA(k0, i); b2[i] = LOADB(k0, i); }
#pragma unroll
    for (int mt = 0; mt < 4; ++mt)
#pragma unroll
      for (int nt = 0; nt < 4; ++nt)
        acc[mt][nt] = __builtin_amdgcn_mfma_f32_16x16x32_bf16(a[mt], b[nt], acc[mt][nt], 0, 0, 0);
#pragma unroll
    for (int i = 0; i < 4; ++i) { a[i] = a2[i]; b[i] = b2[i]; }
  }
#pragma unroll
  for (int mt = 0; mt < 4; ++mt)
#pragma unroll
    for (int nt = 0; nt < 4; ++nt)
      acc[mt][nt] = __builtin_amdgcn_mfma_f32_16x16x32_bf16(a[mt], b[nt], acc[mt][nt], 0, 0, 0);

  // C/D layout: row = (lane>>4)*4 + r, col = lane&15
  const int r0 = (lane >> 4) * 4;
  const int c = lane & 15;
#pragma unroll
  for (int mt = 0; mt < 4; ++mt) {
#pragma unroll
    for (int nt = 0; nt < 4; ++nt) {
      int n = nbase + nt*16 + c;
      if (n < NOUT_) {
        int mrow = mbase + mt*16 + r0;
#pragma unroll
        for (int r = 0; r < 4; ++r)
          out[(size_t)(mrow + r)*NOUT_ + n] = acc[mt][nt][r];
      }
    }
  }
#undef LOADA
#undef LOADB
}

// ---------------------------------------------------------------------------
extern "C" void kernel_launch(void* const* d_in, const int* in_sizes, int n_in,
                              void* d_out, int out_size, void* d_ws, size_t ws_size,
                              hipStream_t stream) {
  // setup_inputs order: subwords, bert_lens, bert_mask, hidden_states,
  //                     mix_weights, gamma, proj_w
  const int*   lens   = (const int*)d_in[1];
  const float* hidden = (const float*)d_in[3];
  const float* mixw   = (const float*)d_in[4];
  const float* gamma  = (const float*)d_in[5];
  const float* projw  = (const float*)d_in[6];
  float* out = (float*)d_out;

  char* ws = (char*)d_ws;
  int* starts = (int*)ws;                                        // 32 KB
  unsigned short* wp     = (unsigned short*)(ws + 32768);        // 768 KB (512x768 bf16 tiled)
  unsigned short* pooled = (unsigned short*)(ws + 32768 + 786432); // 12.6 MB (8192x768 bf16 tiled)

  prep_kernel<<<dim3(224), dim3(256), 0, stream>>>(lens, projw, starts, wp);
  pool_kernel<<<dim3(M_), dim3(192), 0, stream>>>(lens, starts, hidden, mixw, gamma, pooled);
  gemm_kernel<<<dim3(M_/128, NPAD_/128), dim3(256), 0, stream>>>(pooled, wp, out);
}

// Round 2
// 289.581 us; speedup vs baseline: 1.0207x; 1.0207x over previous
//
#include <hip/hip_runtime.h>
#include <hip/hip_bf16.h>
#include <stdint.h>

// Problem constants
#define B_    32
#define SW_   512
#define SL_   256
#define H_    768
#define NL_   4
#define NOUT_ 400
#define M_    (B_*SL_)   // 8192 pooled rows
#define NPAD_ 448        // N padded to 7 x 64-wide tiles (covers 400)

// Tiled (MFMA fragment-linear) layout for a [R][768] bf16 matrix:
//   elem (r, k) -> ((r>>4)*(H_/8) + (k>>3))*128 + (r&15)*8 + (k&7)
// A 16x32 MFMA fragment (rows [rt*16,+16), k [k0,+32)) is the contiguous
// 1024B chunk at ((rt*96 + k0/8)*128) shorts; lane L reads 16B at +L*8 shorts.

typedef __attribute__((ext_vector_type(4))) float  f32x4;
typedef __attribute__((ext_vector_type(8))) short  bf16x8;
typedef __attribute__((ext_vector_type(4))) short  bf16x4;

__device__ __forceinline__ unsigned short f2bf(float f) {
  union { float f; unsigned int u; } x; x.f = f;
  unsigned int u = x.u;
  return (unsigned short)((u + 0x7fffu + ((u >> 16) & 1u)) >> 16);
}

// ---------------------------------------------------------------------------
// Kernel 1 (fused): blocks [0, 8192): pool one word each — inline start
// computation (reduce lens[b,0..j)), softmax mix + gamma + ragged mean,
// write bf16 in MFMA-fragment-linear layout.
// blocks [8192, 8192+224): cast proj_w -> bf16 tiled layout (pad to 448).
// ---------------------------------------------------------------------------
__global__ __launch_bounds__(192) void pool_wcast_kernel(
    const int* __restrict__ lens,
    const float* __restrict__ hidden,
    const float* __restrict__ mixw,
    const float* __restrict__ gamma,
    const float* __restrict__ projw,
    unsigned short* __restrict__ pooled,
    unsigned short* __restrict__ wp) {
  const int t = threadIdx.x;         // 0..191
  if (blockIdx.x >= M_) {
    // weight cast: 224 blocks x 192 threads x 8 = 344064 = 448*768
    const int base = (blockIdx.x - M_) * 1536;
#pragma unroll
    for (int i = 0; i < 8; ++i) {
      int idx = base + i*192 + t;
      int n = idx / H_;
      int k = idx - n*H_;
      float v = (n < NOUT_) ? projw[n*H_ + k] : 0.0f;
      int off = ((n >> 4)*(H_/8) + (k >> 3))*128 + (n & 15)*8 + (k & 7);
      wp[off] = f2bf(v);
    }
    return;
  }

  const int m = blockIdx.x;          // 0..8191
  const int b = m >> 8;
  const int j = m & 255;
  const int* lrow = lens + b * SL_;

  // start = sum(lens[b, 0..j)) — cooperative reduce over 192 threads
  int partial = 0;
  if (t < j) partial += lrow[t];
  if (t + 192 < j) partial += lrow[t + 192];
#pragma unroll
  for (int off = 32; off > 0; off >>= 1)
    partial += __shfl_down(partial, off);
  __shared__ int wsum[3];
  if ((t & 63) == 0) wsum[t >> 6] = partial;
  __syncthreads();
  const int start = wsum[0] + wsum[1] + wsum[2];
  const int len = lrow[j];

  // softmax over 4 mix weights (all-thread redundant, trivial)
  float w0 = mixw[0], w1 = mixw[1], w2 = mixw[2], w3 = mixw[3];
  float mx = fmaxf(fmaxf(w0, w1), fmaxf(w2, w3));
  float ew[NL_];
  ew[0] = __expf(w0 - mx); ew[1] = __expf(w1 - mx);
  ew[2] = __expf(w2 - mx); ew[3] = __expf(w3 - mx);
  float esum = ew[0] + ew[1] + ew[2] + ew[3];
  int cnt = (len > 0) ? len : 1;
  float scale = gamma[0] / (esum * (float)cnt);

  f32x4 acc = {0.0f, 0.0f, 0.0f, 0.0f};
  for (int p = 0; p < len; ++p) {
#pragma unroll
    for (int l = 0; l < NL_; ++l) {
      const f32x4* src = reinterpret_cast<const f32x4*>(
          hidden + ((size_t)(l*B_ + b)*SW_ + (size_t)(start + p)) * H_);
      acc += src[t] * ew[l];
    }
  }

  const int k = t * 4;
  const int off = ((m >> 4)*(H_/8) + (k >> 3))*128 + (m & 15)*8 + (k & 7);
  bf16x4 o;
  o[0] = (short)f2bf(acc[0] * scale);
  o[1] = (short)f2bf(acc[1] * scale);
  o[2] = (short)f2bf(acc[2] * scale);
  o[3] = (short)f2bf(acc[3] * scale);
  *reinterpret_cast<bf16x4*>(pooled + off) = o;
}

// ---------------------------------------------------------------------------
// Kernel 2: GEMM out[m][n] = sum_k pooled[m][k] * W[n][k], bf16 MFMA 16x16x32.
// Block tile 128x64, 4 waves (2x2), wave tile 64x32 (4x2 16x16 accs).
// Fragments direct from global (fragment-linear, L2/L3-resident), no LDS,
// depth-2 register software pipeline. Grid 64x7 = 448 blocks (~2 blocks/CU).
// ---------------------------------------------------------------------------
__global__ __launch_bounds__(256) void gemm_kernel(
    const unsigned short* __restrict__ pooled,
    const unsigned short* __restrict__ wp,
    float* __restrict__ out) {
  const int lane = threadIdx.x & 63;
  const int wave = threadIdx.x >> 6;
  const int wm = wave >> 1, wn = wave & 1;
  const int mbase = blockIdx.x * 128 + wm * 64;
  const int nbase = blockIdx.y * 64 + wn * 32;
  const int mt0 = mbase >> 4;   // 4 m-tiles
  const int nt0 = nbase >> 4;   // 2 n-tiles

  f32x4 acc[4][2];
#pragma unroll
  for (int i = 0; i < 4; ++i)
#pragma unroll
    for (int jj = 0; jj < 2; ++jj)
      acc[i][jj] = (f32x4){0.0f, 0.0f, 0.0f, 0.0f};

#define LOADA(k0, mt) \
  (*reinterpret_cast<const bf16x8*>(pooled + ((size_t)((mt0 + (mt))*(H_/8) + ((k0) >> 3)))*128 + lane*8))
#define LOADB(k0, nt) \
  (*reinterpret_cast<const bf16x8*>(wp + ((size_t)((nt0 + (nt))*(H_/8) + ((k0) >> 3)))*128 + lane*8))

  bf16x8 aP[4], bP[2], aQ[4], bQ[2];
#pragma unroll
  for (int i = 0; i < 4; ++i) aP[i] = LOADA(0, i);
#pragma unroll
  for (int i = 0; i < 2; ++i) bP[i] = LOADB(0, i);
#pragma unroll
  for (int i = 0; i < 4; ++i) aQ[i] = LOADA(32, i);
#pragma unroll
  for (int i = 0; i < 2; ++i) bQ[i] = LOADB(32, i);

  // pairs of 32-K steps; preloaded pair at k={0,32}; loop loads pair {k0,k0+32}
  for (int k0 = 64; k0 < H_; k0 += 64) {
#pragma unroll
    for (int mt = 0; mt < 4; ++mt)
#pragma unroll
      for (int nt = 0; nt < 2; ++nt)
        acc[mt][nt] = __builtin_amdgcn_mfma_f32_16x16x32_bf16(aP[mt], bP[nt], acc[mt][nt], 0, 0, 0);
#pragma unroll
    for (int i = 0; i < 4; ++i) aP[i] = LOADA(k0, i);
#pragma unroll
    for (int i = 0; i < 2; ++i) bP[i] = LOADB(k0, i);
#pragma unroll
    for (int mt = 0; mt < 4; ++mt)
#pragma unroll
      for (int nt = 0; nt < 2; ++nt)
        acc[mt][nt] = __builtin_amdgcn_mfma_f32_16x16x32_bf16(aQ[mt], bQ[nt], acc[mt][nt], 0, 0, 0);
#pragma unroll
    for (int i = 0; i < 4; ++i) aQ[i] = LOADA(k0 + 32, i);
#pragma unroll
    for (int i = 0; i < 2; ++i) bQ[i] = LOADB(k0 + 32, i);
  }
#pragma unroll
  for (int mt = 0; mt < 4; ++mt)
#pragma unroll
    for (int nt = 0; nt < 2; ++nt) {
      acc[mt][nt] = __builtin_amdgcn_mfma_f32_16x16x32_bf16(aP[mt], bP[nt], acc[mt][nt], 0, 0, 0);
      acc[mt][nt] = __builtin_amdgcn_mfma_f32_16x16x32_bf16(aQ[mt], bQ[nt], acc[mt][nt], 0, 0, 0);
    }
#undef LOADA
#undef LOADB

  // C/D layout: row = (lane>>4)*4 + r, col = lane&15
  const int r0 = (lane >> 4) * 4;
  const int c = lane & 15;
#pragma unroll
  for (int mt = 0; mt < 4; ++mt) {
#pragma unroll
    for (int nt = 0; nt < 2; ++nt) {
      int n = nbase + nt*16 + c;
      if (n < NOUT_) {
        int mrow = mbase + mt*16 + r0;
#pragma unroll
        for (int r = 0; r < 4; ++r)
          out[(size_t)(mrow + r)*NOUT_ + n] = acc[mt][nt][r];
      }
    }
  }
}

// ---------------------------------------------------------------------------
extern "C" void kernel_launch(void* const* d_in, const int* in_sizes, int n_in,
                              void* d_out, int out_size, void* d_ws, size_t ws_size,
                              hipStream_t stream) {
  // setup_inputs order: subwords, bert_lens, bert_mask, hidden_states,
  //                     mix_weights, gamma, proj_w
  const int*   lens   = (const int*)d_in[1];
  const float* hidden = (const float*)d_in[3];
  const float* mixw   = (const float*)d_in[4];
  const float* gamma  = (const float*)d_in[5];
  const float* projw  = (const float*)d_in[6];
  float* out = (float*)d_out;

  char* ws = (char*)d_ws;
  unsigned short* wp     = (unsigned short*)ws;              // 448*768*2 = 688128 B
  unsigned short* pooled = (unsigned short*)(ws + 688128);   // 8192*768*2 = 12.58 MB

  pool_wcast_kernel<<<dim3(M_ + 224), dim3(192), 0, stream>>>(
      lens, hidden, mixw, gamma, projw, pooled, wp);
  gemm_kernel<<<dim3(M_/128, NPAD_/64), dim3(256), 0, stream>>>(pooled, wp, out);
}

// Round 3
// 283.792 us; speedup vs baseline: 1.0415x; 1.0204x over previous
//
#include <hip/hip_runtime.h>
#include <hip/hip_bf16.h>
#include <stdint.h>

// Problem constants
#define B_    32
#define SW_   512
#define SL_   256
#define H_    768
#define NL_   4
#define NOUT_ 400
#define M_    (B_*SL_)   // 8192 pooled rows
#define NPAD_ 448        // N padded to 7 x 64-wide tiles (covers 400)
#define NTILES_ (M_/16)  // 512 row-tiles

// Tiled (MFMA fragment-linear) layout for a [R][768] bf16 matrix:
//   elem (r, k) -> ((r>>4)*(H_/8) + (k>>3))*128 + (r&15)*8 + (k&7)
// A 16x32 MFMA fragment (rows [rt*16,+16), k [k0,+32)) is the contiguous
// 1024B chunk at ((rt*96 + k0/8)*128) shorts; lane L reads 16B at +L*8 shorts.

typedef __attribute__((ext_vector_type(4))) float  f32x4;
typedef __attribute__((ext_vector_type(8))) short  bf16x8;
typedef __attribute__((ext_vector_type(4))) short  bf16x4;

__device__ __forceinline__ unsigned short f2bf(float f) {
  union { float f; unsigned int u; } x; x.f = f;
  unsigned int u = x.u;
  return (unsigned short)((u + 0x7fffu + ((u >> 16) & 1u)) >> 16);
}

// ---------------------------------------------------------------------------
// Kernel 1 (fused):
//  blocks [0, 512): pool one 16-word row-tile each. Compute word starts via
//   block-wide reduce + 16-wide serial scan; softmax mix + gamma + ragged
//   mean into a padded LDS tile; write the tile CONTIGUOUSLY (16 B/lane) in
//   MFMA fragment-linear order — no scattered global writes.
//  blocks [512, 512+112): cast proj_w -> bf16 tiled layout (pad to 448).
// ---------------------------------------------------------------------------
__global__ __launch_bounds__(384) void pool_wcast_kernel(
    const int* __restrict__ lens,
    const float* __restrict__ hidden,
    const float* __restrict__ mixw,
    const float* __restrict__ gamma,
    const float* __restrict__ projw,
    unsigned short* __restrict__ pooled,
    unsigned short* __restrict__ wp) {
  const int t = threadIdx.x;         // 0..383
  if (blockIdx.x >= NTILES_) {
    // weight cast: 112 blocks x 384 threads x 8 = 344064 = 448*768
    const int base = (blockIdx.x - NTILES_) * 3072;
#pragma unroll
    for (int i = 0; i < 8; ++i) {
      int idx = base + i*384 + t;
      int n = idx / H_;
      int k = idx - n*H_;
      float v = (n < NOUT_) ? projw[n*H_ + k] : 0.0f;
      int off = ((n >> 4)*(H_/8) + (k >> 3))*128 + (n & 15)*8 + (k & 7);
      wp[off] = f2bf(v);
    }
    return;
  }

  const int rt = blockIdx.x;         // row-tile 0..511
  const int b  = rt >> 4;            // example
  const int j0 = (rt & 15) << 4;     // first word index in example
  const int* lrow = lens + b * SL_;

  __shared__ int s_start[16];
  __shared__ int s_len[16];
  __shared__ int s_wred[6];
  __shared__ unsigned short s_tile[16][H_ + 8];   // +8 shorts pad per row

  // prefix = sum(lens[b, 0..j0)), j0 <= 240 < 384
  int partial = (t < j0) ? lrow[t] : 0;
#pragma unroll
  for (int off = 32; off > 0; off >>= 1)
    partial += __shfl_down(partial, off);
  if ((t & 63) == 0) s_wred[t >> 6] = partial;
  if (t < 16) s_len[t] = lrow[j0 + t];
  __syncthreads();
  if (t == 0) {
    int s = s_wred[0] + s_wred[1] + s_wred[2] + s_wred[3] + s_wred[4] + s_wred[5];
#pragma unroll
    for (int w = 0; w < 16; ++w) { s_start[w] = s; s += s_len[w]; }
  }

  // softmax over 4 mix weights (all-thread redundant, trivial)
  float w0 = mixw[0], w1 = mixw[1], w2 = mixw[2], w3 = mixw[3];
  float mx = fmaxf(fmaxf(w0, w1), fmaxf(w2, w3));
  float ew[NL_];
  ew[0] = __expf(w0 - mx); ew[1] = __expf(w1 - mx);
  ew[2] = __expf(w2 - mx); ew[3] = __expf(w3 - mx);
  float esum = ew[0] + ew[1] + ew[2] + ew[3];
  const float gsc = gamma[0] / esum;
  __syncthreads();

  // Two 192-thread groups; group g handles words w = 2*w8 + g (8 words).
  const int g = t / 192;
  const int u = t - g * 192;         // 0..191, column group: floats 4u..4u+3
#pragma unroll 2
  for (int w8 = 0; w8 < 8; ++w8) {
    const int w = w8*2 + g;
    const int len = s_len[w];
    const int st  = s_start[w];
    f32x4 acc = {0.0f, 0.0f, 0.0f, 0.0f};
    for (int p = 0; p < len; ++p) {
#pragma unroll
      for (int l = 0; l < NL_; ++l) {
        const f32x4* src = reinterpret_cast<const f32x4*>(
            hidden + ((size_t)(l*B_ + b)*SW_ + (size_t)(st + p)) * H_);
        acc += src[u] * ew[l];
      }
    }
    const float sc = gsc / (float)((len > 0) ? len : 1);
    bf16x4 o;
    o[0] = (short)f2bf(acc[0] * sc);
    o[1] = (short)f2bf(acc[1] * sc);
    o[2] = (short)f2bf(acc[2] * sc);
    o[3] = (short)f2bf(acc[3] * sc);
    *reinterpret_cast<bf16x4*>(&s_tile[w][u*4]) = o;
  }
  __syncthreads();

  // Contiguous tile write: 96 chunks x 128 shorts = 12288 shorts.
  // idx = c*128 + r*8 + kk  <->  s_tile[r][c*8 + kk]
  unsigned short* dst = pooled + (size_t)rt * (96*128);
#pragma unroll
  for (int i = 0; i < 4; ++i) {
    int idx = i*3072 + t*8;
    int c = idx >> 7;
    int r = (idx & 127) >> 3;
    bf16x8 v = *reinterpret_cast<const bf16x8*>(&s_tile[r][c*8]);
    *reinterpret_cast<bf16x8*>(dst + idx) = v;
  }
}

// ---------------------------------------------------------------------------
// Kernel 2: GEMM out[m][n] = sum_k pooled[m][k] * W[n][k], bf16 MFMA 16x16x32.
// Block tile 128x64, 4 waves (2x2), wave tile 64x32 (4x2 16x16 accs).
// Fragments direct from global (fragment-linear, L2/L3-resident), no LDS,
// depth-2 register software pipeline. Grid 64x7 = 448 blocks (~2 blocks/CU).
// ---------------------------------------------------------------------------
__global__ __launch_bounds__(256) void gemm_kernel(
    const unsigned short* __restrict__ pooled,
    const unsigned short* __restrict__ wp,
    float* __restrict__ out) {
  const int lane = threadIdx.x & 63;
  const int wave = threadIdx.x >> 6;
  const int wm = wave >> 1, wn = wave & 1;
  const int mbase = blockIdx.x * 128 + wm * 64;
  const int nbase = blockIdx.y * 64 + wn * 32;
  const int mt0 = mbase >> 4;   // 4 m-tiles
  const int nt0 = nbase >> 4;   // 2 n-tiles

  f32x4 acc[4][2];
#pragma unroll
  for (int i = 0; i < 4; ++i)
#pragma unroll
    for (int jj = 0; jj < 2; ++jj)
      acc[i][jj] = (f32x4){0.0f, 0.0f, 0.0f, 0.0f};

#define LOADA(k0, mt) \
  (*reinterpret_cast<const bf16x8*>(pooled + ((size_t)((mt0 + (mt))*(H_/8) + ((k0) >> 3)))*128 + lane*8))
#define LOADB(k0, nt) \
  (*reinterpret_cast<const bf16x8*>(wp + ((size_t)((nt0 + (nt))*(H_/8) + ((k0) >> 3)))*128 + lane*8))

  bf16x8 aP[4], bP[2], aQ[4], bQ[2];
#pragma unroll
  for (int i = 0; i < 4; ++i) aP[i] = LOADA(0, i);
#pragma unroll
  for (int i = 0; i < 2; ++i) bP[i] = LOADB(0, i);
#pragma unroll
  for (int i = 0; i < 4; ++i) aQ[i] = LOADA(32, i);
#pragma unroll
  for (int i = 0; i < 2; ++i) bQ[i] = LOADB(32, i);

  for (int k0 = 64; k0 < H_; k0 += 64) {
#pragma unroll
    for (int mt = 0; mt < 4; ++mt)
#pragma unroll
      for (int nt = 0; nt < 2; ++nt)
        acc[mt][nt] = __builtin_amdgcn_mfma_f32_16x16x32_bf16(aP[mt], bP[nt], acc[mt][nt], 0, 0, 0);
#pragma unroll
    for (int i = 0; i < 4; ++i) aP[i] = LOADA(k0, i);
#pragma unroll
    for (int i = 0; i < 2; ++i) bP[i] = LOADB(k0, i);
#pragma unroll
    for (int mt = 0; mt < 4; ++mt)
#pragma unroll
      for (int nt = 0; nt < 2; ++nt)
        acc[mt][nt] = __builtin_amdgcn_mfma_f32_16x16x32_bf16(aQ[mt], bQ[nt], acc[mt][nt], 0, 0, 0);
#pragma unroll
    for (int i = 0; i < 4; ++i) aQ[i] = LOADA(k0 + 32, i);
#pragma unroll
    for (int i = 0; i < 2; ++i) bQ[i] = LOADB(k0 + 32, i);
  }
#pragma unroll
  for (int mt = 0; mt < 4; ++mt)
#pragma unroll
    for (int nt = 0; nt < 2; ++nt) {
      acc[mt][nt] = __builtin_amdgcn_mfma_f32_16x16x32_bf16(aP[mt], bP[nt], acc[mt][nt], 0, 0, 0);
      acc[mt][nt] = __builtin_amdgcn_mfma_f32_16x16x32_bf16(aQ[mt], bQ[nt], acc[mt][nt], 0, 0, 0);
    }
#undef LOADA
#undef LOADB

  // C/D layout: row = (lane>>4)*4 + r, col = lane&15
  const int r0 = (lane >> 4) * 4;
  const int c = lane & 15;
#pragma unroll
  for (int mt = 0; mt < 4; ++mt) {
#pragma unroll
    for (int nt = 0; nt < 2; ++nt) {
      int n = nbase + nt*16 + c;
      if (n < NOUT_) {
        int mrow = mbase + mt*16 + r0;
#pragma unroll
        for (int r = 0; r < 4; ++r)
          out[(size_t)(mrow + r)*NOUT_ + n] = acc[mt][nt][r];
      }
    }
  }
}

// ---------------------------------------------------------------------------
extern "C" void kernel_launch(void* const* d_in, const int* in_sizes, int n_in,
                              void* d_out, int out_size, void* d_ws, size_t ws_size,
                              hipStream_t stream) {
  // setup_inputs order: subwords, bert_lens, bert_mask, hidden_states,
  //                     mix_weights, gamma, proj_w
  const int*   lens   = (const int*)d_in[1];
  const float* hidden = (const float*)d_in[3];
  const float* mixw   = (const float*)d_in[4];
  const float* gamma  = (const float*)d_in[5];
  const float* projw  = (const float*)d_in[6];
  float* out = (float*)d_out;

  char* ws = (char*)d_ws;
  unsigned short* wp     = (unsigned short*)ws;              // 448*768*2 = 688128 B
  unsigned short* pooled = (unsigned short*)(ws + 688128);   // 8192*768*2 = 12.58 MB

  pool_wcast_kernel<<<dim3(NTILES_ + 112), dim3(384), 0, stream>>>(
      lens, hidden, mixw, gamma, projw, pooled, wp);
  gemm_kernel<<<dim3(M_/128, NPAD_/64), dim3(256), 0, stream>>>(pooled, wp, out);
}

// Round 4
// 283.687 us; speedup vs baseline: 1.0419x; 1.0004x over previous
//
#include <hip/hip_runtime.h>
#include <hip/hip_bf16.h>
#include <stdint.h>

// Problem constants
#define B_    32
#define SW_   512
#define SL_   256
#define H_    768
#define NL_   4
#define NOUT_ 400
#define M_    (B_*SL_)   // 8192 pooled rows
#define NPAD_ 448        // N padded to 7 x 64-wide tiles (covers 400)
#define NTILES_ (M_/16)  // 512 row-tiles
#define PBLOCKS_ (2*NTILES_)  // 1024 pool half-blocks

// Tiled (MFMA fragment-linear) layout for a [R][768] bf16 matrix:
//   elem (r, k) -> ((r>>4)*(H_/8) + (k>>3))*128 + (r&15)*8 + (k&7)
// A 16x32 MFMA fragment (rows [rt*16,+16), k [k0,+32)) is the contiguous
// 1024B chunk at ((rt*96 + k0/8)*128) shorts; lane L reads 16B at +L*8 shorts.

typedef __attribute__((ext_vector_type(4))) float  f32x4;
typedef __attribute__((ext_vector_type(8))) short  bf16x8;
typedef __attribute__((ext_vector_type(4))) short  bf16x4;

__device__ __forceinline__ unsigned short f2bf(float f) {
  union { float f; unsigned int u; } x; x.f = f;
  unsigned int u = x.u;
  return (unsigned short)((u + 0x7fffu + ((u >> 16) & 1u)) >> 16);
}

// ---------------------------------------------------------------------------
// Kernel 1 (fused):
//  blocks [0, 1024): pool an 8-word half of a 16-row tile (2 blocks/tile for
//   occupancy: ~4 blocks/CU, 24 waves/CU). Word starts via block reduce +
//   8-wide serial scan; softmax mix + gamma + ragged mean into LDS; write
//   the half-tile as 128B-aligned contiguous 128B pieces in fragment-linear
//   order (rows h*8..h*8+7 of each 128-short chunk).
//  blocks [1024, 1024+112): cast proj_w -> bf16 tiled layout (pad to 448).
// ---------------------------------------------------------------------------
__global__ __launch_bounds__(384) void pool_wcast_kernel(
    const int* __restrict__ lens,
    const float* __restrict__ hidden,
    const float* __restrict__ mixw,
    const float* __restrict__ gamma,
    const float* __restrict__ projw,
    unsigned short* __restrict__ pooled,
    unsigned short* __restrict__ wp) {
  const int t = threadIdx.x;         // 0..383
  if (blockIdx.x >= PBLOCKS_) {
    // weight cast: 112 blocks x 384 threads x 8 = 344064 = 448*768
    const int base = (blockIdx.x - PBLOCKS_) * 3072;
#pragma unroll
    for (int i = 0; i < 8; ++i) {
      int idx = base + i*384 + t;
      int n = idx / H_;
      int k = idx - n*H_;
      float v = (n < NOUT_) ? projw[n*H_ + k] : 0.0f;
      int off = ((n >> 4)*(H_/8) + (k >> 3))*128 + (n & 15)*8 + (k & 7);
      wp[off] = f2bf(v);
    }
    return;
  }

  const int blk = blockIdx.x;        // 0..1023
  const int rt  = blk >> 1;          // row-tile 0..511
  const int h   = blk & 1;           // half: rows h*8 .. h*8+7 of the tile
  const int b   = rt >> 4;           // example
  const int j0  = ((rt & 15) << 4) + h*8;  // first of 8 words
  const int* lrow = lens + b * SL_;

  __shared__ int s_start[8];
  __shared__ int s_len[8];
  __shared__ int s_wred[6];
  __shared__ unsigned short s_tile[8][H_ + 8];   // +8 shorts pad per row

  // prefix = sum(lens[b, 0..j0)), j0 <= 248 < 384
  int partial = (t < j0) ? lrow[t] : 0;
#pragma unroll
  for (int off = 32; off > 0; off >>= 1)
    partial += __shfl_down(partial, off);
  if ((t & 63) == 0) s_wred[t >> 6] = partial;
  if (t < 8) s_len[t] = lrow[j0 + t];
  __syncthreads();
  if (t == 0) {
    int s = s_wred[0] + s_wred[1] + s_wred[2] + s_wred[3] + s_wred[4] + s_wred[5];
#pragma unroll
    for (int w = 0; w < 8; ++w) { s_start[w] = s; s += s_len[w]; }
  }

  // softmax over 4 mix weights (all-thread redundant, trivial)
  float w0 = mixw[0], w1 = mixw[1], w2 = mixw[2], w3 = mixw[3];
  float mx = fmaxf(fmaxf(w0, w1), fmaxf(w2, w3));
  float ew[NL_];
  ew[0] = __expf(w0 - mx); ew[1] = __expf(w1 - mx);
  ew[2] = __expf(w2 - mx); ew[3] = __expf(w3 - mx);
  float esum = ew[0] + ew[1] + ew[2] + ew[3];
  const float gsc = gamma[0] / esum;
  __syncthreads();

  // Two 192-thread (3-wave) groups; group g handles words w = 2*w4 + g.
  const int g = t / 192;
  const int u = t - g * 192;         // 0..191, covers floats 4u..4u+3
#pragma unroll
  for (int w4 = 0; w4 < 4; ++w4) {
    const int w = w4*2 + g;
    const int len = s_len[w];
    const int st  = s_start[w];
    f32x4 acc = {0.0f, 0.0f, 0.0f, 0.0f};
    for (int p = 0; p < len; ++p) {
#pragma unroll
      for (int l = 0; l < NL_; ++l) {
        const f32x4* src = reinterpret_cast<const f32x4*>(
            hidden + ((size_t)(l*B_ + b)*SW_ + (size_t)(st + p)) * H_);
        acc += src[u] * ew[l];
      }
    }
    const float sc = gsc / (float)((len > 0) ? len : 1);
    bf16x4 o;
    o[0] = (short)f2bf(acc[0] * sc);
    o[1] = (short)f2bf(acc[1] * sc);
    o[2] = (short)f2bf(acc[2] * sc);
    o[3] = (short)f2bf(acc[3] * sc);
    *reinterpret_cast<bf16x4*>(&s_tile[w][u*4]) = o;
  }
  __syncthreads();

  // Half-tile write: 96 chunks; this half writes shorts [c*128 + h*64,
  // +64) of each chunk (rows h*8..h*8+7). 6144 shorts = 384 thr x 16.
  unsigned short* dst = pooled + (size_t)rt * (96*128) + h*64;
  {
    const int i = t * 16;
    const int c = i >> 6;            // chunk 0..95
    const int off = i & 63;          // 0,16,32,48
    const int rl = off >> 3;         // 0,2,4,6
    bf16x8 v0 = *reinterpret_cast<const bf16x8*>(&s_tile[rl][c*8]);
    bf16x8 v1 = *reinterpret_cast<const bf16x8*>(&s_tile[rl + 1][c*8]);
    *reinterpret_cast<bf16x8*>(dst + (size_t)c*128 + off)     = v0;
    *reinterpret_cast<bf16x8*>(dst + (size_t)c*128 + off + 8) = v1;
  }
}

// ---------------------------------------------------------------------------
// Kernel 2: GEMM out[m][n] = sum_k pooled[m][k] * W[n][k], bf16 MFMA 16x16x32.
// Block tile 128x64, 4 waves (2x2), wave tile 64x32 (4x2 16x16 accs).
// Fragments direct from global (fragment-linear, L2/L3-resident), no LDS,
// depth-2 register software pipeline. Grid 64x7 = 448 blocks (~2 blocks/CU).
// ---------------------------------------------------------------------------
__global__ __launch_bounds__(256) void gemm_kernel(
    const unsigned short* __restrict__ pooled,
    const unsigned short* __restrict__ wp,
    float* __restrict__ out) {
  const int lane = threadIdx.x & 63;
  const int wave = threadIdx.x >> 6;
  const int wm = wave >> 1, wn = wave & 1;
  const int mbase = blockIdx.x * 128 + wm * 64;
  const int nbase = blockIdx.y * 64 + wn * 32;
  const int mt0 = mbase >> 4;   // 4 m-tiles
  const int nt0 = nbase >> 4;   // 2 n-tiles

  f32x4 acc[4][2];
#pragma unroll
  for (int i = 0; i < 4; ++i)
#pragma unroll
    for (int jj = 0; jj < 2; ++jj)
      acc[i][jj] = (f32x4){0.0f, 0.0f, 0.0f, 0.0f};

#define LOADA(k0, mt) \
  (*reinterpret_cast<const bf16x8*>(pooled + ((size_t)((mt0 + (mt))*(H_/8) + ((k0) >> 3)))*128 + lane*8))
#define LOADB(k0, nt) \
  (*reinterpret_cast<const bf16x8*>(wp + ((size_t)((nt0 + (nt))*(H_/8) + ((k0) >> 3)))*128 + lane*8))

  bf16x8 aP[4], bP[2], aQ[4], bQ[2];
#pragma unroll
  for (int i = 0; i < 4; ++i) aP[i] = LOADA(0, i);
#pragma unroll
  for (int i = 0; i < 2; ++i) bP[i] = LOADB(0, i);
#pragma unroll
  for (int i = 0; i < 4; ++i) aQ[i] = LOADA(32, i);
#pragma unroll
  for (int i = 0; i < 2; ++i) bQ[i] = LOADB(32, i);

  for (int k0 = 64; k0 < H_; k0 += 64) {
#pragma unroll
    for (int mt = 0; mt < 4; ++mt)
#pragma unroll
      for (int nt = 0; nt < 2; ++nt)
        acc[mt][nt] = __builtin_amdgcn_mfma_f32_16x16x32_bf16(aP[mt], bP[nt], acc[mt][nt], 0, 0, 0);
#pragma unroll
    for (int i = 0; i < 4; ++i) aP[i] = LOADA(k0, i);
#pragma unroll
    for (int i = 0; i < 2; ++i) bP[i] = LOADB(k0, i);
#pragma unroll
    for (int mt = 0; mt < 4; ++mt)
#pragma unroll
      for (int nt = 0; nt < 2; ++nt)
        acc[mt][nt] = __builtin_amdgcn_mfma_f32_16x16x32_bf16(aQ[mt], bQ[nt], acc[mt][nt], 0, 0, 0);
#pragma unroll
    for (int i = 0; i < 4; ++i) aQ[i] = LOADA(k0 + 32, i);
#pragma unroll
    for (int i = 0; i < 2; ++i) bQ[i] = LOADB(k0 + 32, i);
  }
#pragma unroll
  for (int mt = 0; mt < 4; ++mt)
#pragma unroll
    for (int nt = 0; nt < 2; ++nt) {
      acc[mt][nt] = __builtin_amdgcn_mfma_f32_16x16x32_bf16(aP[mt], bP[nt], acc[mt][nt], 0, 0, 0);
      acc[mt][nt] = __builtin_amdgcn_mfma_f32_16x16x32_bf16(aQ[mt], bQ[nt], acc[mt][nt], 0, 0, 0);
    }
#undef LOADA
#undef LOADB

  // C/D layout: row = (lane>>4)*4 + r, col = lane&15
  const int r0 = (lane >> 4) * 4;
  const int c = lane & 15;
#pragma unroll
  for (int mt = 0; mt < 4; ++mt) {
#pragma unroll
    for (int nt = 0; nt < 2; ++nt) {
      int n = nbase + nt*16 + c;
      if (n < NOUT_) {
        int mrow = mbase + mt*16 + r0;
#pragma unroll
        for (int r = 0; r < 4; ++r)
          __builtin_nontemporal_store(acc[mt][nt][r],
                                      &out[(size_t)(mrow + r)*NOUT_ + n]);
      }
    }
  }
}

// ---------------------------------------------------------------------------
extern "C" void kernel_launch(void* const* d_in, const int* in_sizes, int n_in,
                              void* d_out, int out_size, void* d_ws, size_t ws_size,
                              hipStream_t stream) {
  // setup_inputs order: subwords, bert_lens, bert_mask, hidden_states,
  //                     mix_weights, gamma, proj_w
  const int*   lens   = (const int*)d_in[1];
  const float* hidden = (const float*)d_in[3];
  const float* mixw   = (const float*)d_in[4];
  const float* gamma  = (const float*)d_in[5];
  const float* projw  = (const float*)d_in[6];
  float* out = (float*)d_out;

  char* ws = (char*)d_ws;
  unsigned short* wp     = (unsigned short*)ws;              // 448*768*2 = 688128 B
  unsigned short* pooled = (unsigned short*)(ws + 688128);   // 8192*768*2 = 12.58 MB

  pool_wcast_kernel<<<dim3(PBLOCKS_ + 112), dim3(384), 0, stream>>>(
      lens, hidden, mixw, gamma, projw, pooled, wp);
  gemm_kernel<<<dim3(M_/128, NPAD_/64), dim3(256), 0, stream>>>(pooled, wp, out);
}

// Round 5
// 279.621 us; speedup vs baseline: 1.0570x; 1.0145x over previous
//
#include <hip/hip_runtime.h>
#include <hip/hip_bf16.h>
#include <stdint.h>

// Problem constants
#define B_    32
#define SW_   512
#define SL_   256
#define H_    768
#define NL_   4
#define NOUT_ 400
#define M_    (B_*SL_)   // 8192 pooled rows
#define NPAD_ 448        // N padded to 7 x 64-wide wave slices (covers 400)
#define ROWPAD_ 776      // LDS row stride in shorts (768 + 8 pad)

// B-weight tiled (MFMA fragment-linear) layout for the [448][768] bf16 matrix:
//   elem (n, k) -> ((n>>4)*(H_/8) + (k>>3))*128 + (n&15)*8 + (k&7)
// A 16x32 fragment (n-tile nt, k [k0,+32)) is the contiguous 1024B chunk at
// ((nt*96 + k0/8)*128) shorts; lane L reads 16B at +L*8 shorts.

typedef __attribute__((ext_vector_type(4))) float  f32x4;
typedef __attribute__((ext_vector_type(8))) short  bf16x8;
typedef __attribute__((ext_vector_type(4))) short  bf16x4;

__device__ __forceinline__ unsigned short f2bf(float f) {
  union { float f; unsigned int u; } x; x.f = f;
  unsigned int u = x.u;
  return (unsigned short)((u + 0x7fffu + ((u >> 16) & 1u)) >> 16);
}

// ---------------------------------------------------------------------------
// Kernel 1: cast proj_w -> bf16 fragment-linear layout (pad N to 448).
// 168 blocks x 256 threads x 8 elems = 344064 = 448*768.
// ---------------------------------------------------------------------------
__global__ __launch_bounds__(256) void wcast_kernel(
    const float* __restrict__ projw, unsigned short* __restrict__ wp) {
  const int t = threadIdx.x;
  const int base = blockIdx.x * 2048;
#pragma unroll
  for (int i = 0; i < 8; ++i) {
    int idx = base + i*256 + t;
    int n = idx / H_;
    int k = idx - n*H_;
    float v = (n < NOUT_) ? projw[n*H_ + k] : 0.0f;
    int off = ((n >> 4)*(H_/8) + (k >> 3))*128 + (n & 15)*8 + (k & 7);
    wp[off] = f2bf(v);
  }
}

// ---------------------------------------------------------------------------
// Kernel 2 (fused pool + GEMM): one block per 32 pooled rows. Grid 256,
// 448 threads (7 waves).
//  Phase 1: word starts via block reduce + 32-wide serial scan; softmax mix
//   + gamma + ragged mean into a padded row-major LDS tile (48.5 KB). No
//   global writes for A at all.
//  Phase 2: wave w computes out[32 x 64] for N slice [w*64,+64):
//   A-frags ds_read_b128 from LDS (2-way bank aliasing = free), B-frags
//   bf16x8 from wp (L2-resident), MFMA 16x16x32 bf16, depth-2 K-pipeline.
// ---------------------------------------------------------------------------
__global__ __launch_bounds__(448) void fused_kernel(
    const int* __restrict__ lens,
    const float* __restrict__ hidden,
    const float* __restrict__ mixw,
    const float* __restrict__ gamma,
    const unsigned short* __restrict__ wp,
    float* __restrict__ out) {
  const int t  = threadIdx.x;        // 0..447
  const int rt = blockIdx.x;         // 0..255 (32-row tile)
  const int b  = rt >> 3;            // example
  const int j0 = (rt & 7) << 5;      // first of 32 words, <= 224
  const int* lrow = lens + b * SL_;

  __shared__ int s_start[32];
  __shared__ int s_len[32];
  __shared__ int s_wred[7];
  __shared__ __align__(16) unsigned short s_tile[32][ROWPAD_];

  // prefix = sum(lens[b, 0..j0)), j0 <= 224 < 448
  int partial = (t < j0) ? lrow[t] : 0;
#pragma unroll
  for (int off = 32; off > 0; off >>= 1)
    partial += __shfl_down(partial, off);
  if ((t & 63) == 0) s_wred[t >> 6] = partial;
  if (t < 32) s_len[t] = lrow[j0 + t];
  __syncthreads();
  if (t == 0) {
    int s = s_wred[0] + s_wred[1] + s_wred[2] + s_wred[3] + s_wred[4] +
            s_wred[5] + s_wred[6];
#pragma unroll
    for (int w = 0; w < 32; ++w) { s_start[w] = s; s += s_len[w]; }
  }

  // softmax over 4 mix weights (all-thread redundant, trivial)
  float w0 = mixw[0], w1 = mixw[1], w2 = mixw[2], w3 = mixw[3];
  float mx = fmaxf(fmaxf(w0, w1), fmaxf(w2, w3));
  float ew[NL_];
  ew[0] = __expf(w0 - mx); ew[1] = __expf(w1 - mx);
  ew[2] = __expf(w2 - mx); ew[3] = __expf(w3 - mx);
  float esum = ew[0] + ew[1] + ew[2] + ew[3];
  const float gsc = gamma[0] / esum;
  __syncthreads();

  // ---- Phase 1: pool 32 words. Two 192-thread groups; group g does word
  // w = 2*it + g; thread u covers floats 4u..4u+3 of the 768. 16 iters.
  if (t < 384) {
    const int g = t / 192;
    const int u = t - g * 192;
#pragma unroll 2
    for (int it = 0; it < 16; ++it) {
      const int w = it*2 + g;
      const int len = s_len[w];
      const int st  = s_start[w];
      f32x4 acc = {0.0f, 0.0f, 0.0f, 0.0f};
      for (int p = 0; p < len; ++p) {
#pragma unroll
        for (int l = 0; l < NL_; ++l) {
          const f32x4* src = reinterpret_cast<const f32x4*>(
              hidden + ((size_t)(l*B_ + b)*SW_ + (size_t)(st + p)) * H_);
          acc += src[u] * ew[l];
        }
      }
      const float sc = gsc / (float)((len > 0) ? len : 1);
      bf16x4 o;
      o[0] = (short)f2bf(acc[0] * sc);
      o[1] = (short)f2bf(acc[1] * sc);
      o[2] = (short)f2bf(acc[2] * sc);
      o[3] = (short)f2bf(acc[3] * sc);
      *reinterpret_cast<bf16x4*>(&s_tile[w][u*4]) = o;
    }
  }
  __syncthreads();

  // ---- Phase 2: GEMM. Wave w -> N slice [w*64, +64): 2 m-tiles x 4 n-tiles.
  const int lane = t & 63;
  const int wv = t >> 6;             // 0..6
  const int nbase = wv * 64;
  const int nt0 = wv * 4;            // B chunk-row base

  f32x4 acc[2][4];
#pragma unroll
  for (int i = 0; i < 2; ++i)
#pragma unroll
    for (int j = 0; j < 4; ++j)
      acc[i][j] = (f32x4){0.0f, 0.0f, 0.0f, 0.0f};

  // A fragment: lane L -> A[m = mt*16 + (L&15)][k = k0 + (L>>4)*8 .. +8]
#define LDA(k0, mt) \
  (*reinterpret_cast<const bf16x8*>(&s_tile[(mt)*16 + (lane & 15)][(k0) + (lane >> 4)*8]))
#define LDB(k0, nt) \
  (*reinterpret_cast<const bf16x8*>(wp + ((size_t)((nt0 + (nt))*(H_/8) + ((k0) >> 3)))*128 + lane*8))

  bf16x8 aP[2], bP[4], aQ[2], bQ[4];
#pragma unroll
  for (int i = 0; i < 2; ++i) aP[i] = LDA(0, i);
#pragma unroll
  for (int i = 0; i < 4; ++i) bP[i] = LDB(0, i);
#pragma unroll
  for (int i = 0; i < 2; ++i) aQ[i] = LDA(32, i);
#pragma unroll
  for (int i = 0; i < 4; ++i) bQ[i] = LDB(32, i);

  for (int k0 = 64; k0 < H_; k0 += 64) {
#pragma unroll
    for (int mt = 0; mt < 2; ++mt)
#pragma unroll
      for (int nt = 0; nt < 4; ++nt)
        acc[mt][nt] = __builtin_amdgcn_mfma_f32_16x16x32_bf16(aP[mt], bP[nt], acc[mt][nt], 0, 0, 0);
#pragma unroll
    for (int i = 0; i < 2; ++i) aP[i] = LDA(k0, i);
#pragma unroll
    for (int i = 0; i < 4; ++i) bP[i] = LDB(k0, i);
#pragma unroll
    for (int mt = 0; mt < 2; ++mt)
#pragma unroll
      for (int nt = 0; nt < 4; ++nt)
        acc[mt][nt] = __builtin_amdgcn_mfma_f32_16x16x32_bf16(aQ[mt], bQ[nt], acc[mt][nt], 0, 0, 0);
#pragma unroll
    for (int i = 0; i < 2; ++i) aQ[i] = LDA(k0 + 32, i);
#pragma unroll
    for (int i = 0; i < 4; ++i) bQ[i] = LDB(k0 + 32, i);
  }
#pragma unroll
  for (int mt = 0; mt < 2; ++mt)
#pragma unroll
    for (int nt = 0; nt < 4; ++nt) {
      acc[mt][nt] = __builtin_amdgcn_mfma_f32_16x16x32_bf16(aP[mt], bP[nt], acc[mt][nt], 0, 0, 0);
      acc[mt][nt] = __builtin_amdgcn_mfma_f32_16x16x32_bf16(aQ[mt], bQ[nt], acc[mt][nt], 0, 0, 0);
    }
#undef LDA
#undef LDB

  // C/D layout: row = (lane>>4)*4 + r, col = lane&15
  const int r0 = (lane >> 4) * 4;
  const int c = lane & 15;
#pragma unroll
  for (int mt = 0; mt < 2; ++mt) {
#pragma unroll
    for (int nt = 0; nt < 4; ++nt) {
      int n = nbase + nt*16 + c;
      if (n < NOUT_) {
        int mrow = rt*32 + mt*16 + r0;
#pragma unroll
        for (int r = 0; r < 4; ++r)
          out[(size_t)(mrow + r)*NOUT_ + n] = acc[mt][nt][r];
      }
    }
  }
}

// ---------------------------------------------------------------------------
extern "C" void kernel_launch(void* const* d_in, const int* in_sizes, int n_in,
                              void* d_out, int out_size, void* d_ws, size_t ws_size,
                              hipStream_t stream) {
  // setup_inputs order: subwords, bert_lens, bert_mask, hidden_states,
  //                     mix_weights, gamma, proj_w
  const int*   lens   = (const int*)d_in[1];
  const float* hidden = (const float*)d_in[3];
  const float* mixw   = (const float*)d_in[4];
  const float* gamma  = (const float*)d_in[5];
  const float* projw  = (const float*)d_in[6];
  float* out = (float*)d_out;

  unsigned short* wp = (unsigned short*)d_ws;   // 448*768*2 = 688128 B

  wcast_kernel<<<dim3(168), dim3(256), 0, stream>>>(projw, wp);
  fused_kernel<<<dim3(256), dim3(448), 0, stream>>>(
      lens, hidden, mixw, gamma, wp, out);
}